// Round 7
// baseline (161.624 us; speedup 1.0000x reference)
//
#include <hip/hip_runtime.h>

// Problem constants
#define NPTS   3000
#define MPTS   3000
#define KNODES 6000
#define HEADS  4
#define FDIM   256      // HEADS*HID
#define OUTC   2
#define R2     0.0025f
#define NSLOPE 0.2f
#define MAXNBR 64
#define RPB    12       // rows per K1 block -> 500 blocks (~2/CU)

// ---------------- workspace layout (floats) ----------------
#define OFF_ES2  0
#define OFF_ED2  24000
#define OFF_H2   48000        // 6000*256
#define OFF_END  1584000      // floats; int region starts at byte 4*OFF_END

// full-wave sum: butterfly xor-reduce, all 64 lanes end with the total
__device__ __forceinline__ float wsum(float x) {
#pragma unroll
    for (int off = 32; off; off >>= 1) x += __shfl_xor(x, off, 64);
    return x;
}

// K1: per block of 12 rows, block-local through h2:
//  A) radius scan (exact fp32 gram-trick ops -> bit-identical mask)
//  B) layer-1 softmax-agg via rank-3 collapse: score_j = dot(p_j, W1^T a)|head
//     -> no per-neighbor reductions; h1_j recomputed (3 fmaf) -> x in LDS
//  C) gemm2: col-per-thread (col=t), 12 rows/wave in registers; W2 read
//     once per block (coalesced dword loads) + layer-2 scores (head=wave)
__global__ __launch_bounds__(256) void k_l1(
        const float* __restrict__ pos, const float* __restrict__ pnm,
        const float* __restrict__ W1, const float* __restrict__ as1,
        const float* __restrict__ ad1, const float* __restrict__ b1,
        const float* __restrict__ W2, const float* __restrict__ as2,
        const float* __restrict__ ad2,
        float* __restrict__ h2, float* __restrict__ es2, float* __restrict__ ed2,
        int* __restrict__ cnt, int* __restrict__ idx) {
    __shared__ int s_cnt[RPB];
    __shared__ int s_idx[RPB][MAXNBR];
    __shared__ __align__(16) float xs[RPB][FDIM];
    const int t = threadIdx.x;
    const int lane = t & 63, wv = t >> 6;
    const int i0 = blockIdx.x * RPB;

    // ---- Phase A: neighbor scan ----
    if (t < RPB) s_cnt[t] = 0;
    __syncthreads();
    // 3000 % RPB == 0 -> a block's rows never straddle pos/pnm
    const float* base = (i0 < NPTS) ? pos : pnm;
    const int ib = (i0 < NPTS) ? i0 : i0 - NPTS;
    float xi[RPB], yi[RPB], zi[RPB], si[RPB];
#pragma unroll
    for (int r = 0; r < RPB; ++r) {
        float x = base[ib + r], y = base[NPTS + ib + r], z = base[2 * NPTS + ib + r];
        xi[r] = x; yi[r] = y; zi[r] = z;
        si[r] = __fadd_rn(__fadd_rn(__fmul_rn(x, x), __fmul_rn(y, y)), __fmul_rn(z, z));
    }
    for (int j = t; j < KNODES; j += 256) {
        float xj, yj, zj;
        if (j < NPTS) { xj = pos[j]; yj = pos[NPTS + j]; zj = pos[2 * NPTS + j]; }
        else { int q = j - NPTS; xj = pnm[q]; yj = pnm[MPTS + q]; zj = pnm[2 * MPTS + q]; }
        float sj = __fadd_rn(__fadd_rn(__fmul_rn(xj, xj), __fmul_rn(yj, yj)),
                             __fmul_rn(zj, zj));
#pragma unroll
        for (int r = 0; r < RPB; ++r) {
            float dot = __fadd_rn(__fadd_rn(__fmul_rn(xi[r], xj), __fmul_rn(yi[r], yj)),
                                  __fmul_rn(zi[r], zj));
            float d2 = __fsub_rn(__fadd_rn(si[r], sj), __fmul_rn(2.0f, dot));
            if (d2 < R2) {
                int p = atomicAdd(&s_cnt[r], 1);
                if (p < MAXNBR) s_idx[r][p] = j;
            }
        }
    }
    __syncthreads();
    if (t < RPB) cnt[i0 + t] = min(s_cnt[t], MAXNBR);
#pragma unroll
    for (int r = 0; r < RPB; ++r) {
        int c = min(s_cnt[r], MAXNBR);
        if (t < c) idx[(i0 + r) * MAXNBR + t] = s_idx[r][t];
    }

    // ---- Phase B: layer-1 agg via rank-3 collapsed scores ----
    const float w1a = W1[t], w1b = W1[FDIM + t], w1c = W1[2 * FDIM + t];
    const float asv = as1[t], adv = ad1[t], b1v = b1[t];
    // per-head 3-vectors u = W1^T a_src|head, v = W1^T a_dst|head
    // (wave = head; xor-reduce leaves the sum in all lanes)
    const float u0 = wsum(w1a * asv), u1 = wsum(w1b * asv), u2 = wsum(w1c * asv);
    const float v0 = wsum(w1a * adv), v1 = wsum(w1b * adv), v2 = wsum(w1c * adv);
    for (int r = 0; r < RPB; ++r) {
        int c = min(s_cnt[r], MAXNBR);
        float dsum = fmaf(xi[r], v0, fmaf(yi[r], v1, zi[r] * v2));
        float m = -1e30f;
        for (int jl = 0; jl < c; ++jl) {
            int j = s_idx[r][jl];
            float xj, yj, zj;
            if (j < NPTS) { xj = pos[j]; yj = pos[NPTS + j]; zj = pos[2 * NPTS + j]; }
            else { int q = j - NPTS; xj = pnm[q]; yj = pnm[MPTS + q]; zj = pnm[2 * MPTS + q]; }
            float e = dsum + fmaf(xj, u0, fmaf(yj, u1, zj * u2));
            e = (e >= 0.f) ? e : NSLOPE * e;
            m = fmaxf(m, e);
        }
        float ssum = 0.f, acc = 0.f;
        for (int jl = 0; jl < c; ++jl) {
            int j = s_idx[r][jl];
            float xj, yj, zj;
            if (j < NPTS) { xj = pos[j]; yj = pos[NPTS + j]; zj = pos[2 * NPTS + j]; }
            else { int q = j - NPTS; xj = pnm[q]; yj = pnm[MPTS + q]; zj = pnm[2 * MPTS + q]; }
            float e = dsum + fmaf(xj, u0, fmaf(yj, u1, zj * u2));
            e = (e >= 0.f) ? e : NSLOPE * e;          // identical sequence -> same bits as pass 1
            float p = __expf(e - m);
            ssum += p;
            float h1j = fmaf(xj, w1a, fmaf(yj, w1b, zj * w1c));
            acc = fmaf(p, h1j, acc);
        }
        xs[r][t] = fmaxf(acc / ssum + b1v, 0.f);
    }
    __syncthreads();

    // ---- Phase C: gemm2, col = t, 12 rows in registers ----
    {
        float acc[RPB];
#pragma unroll
        for (int r = 0; r < RPB; ++r) acc[r] = 0.f;
#pragma unroll 2
        for (int k4 = 0; k4 < FDIM / 4; ++k4) {
            float w0 = W2[(4 * k4 + 0) * FDIM + t];   // block-coalesced 1KB/k
            float w1 = W2[(4 * k4 + 1) * FDIM + t];
            float w2 = W2[(4 * k4 + 2) * FDIM + t];
            float w3 = W2[(4 * k4 + 3) * FDIM + t];
#pragma unroll
            for (int r = 0; r < RPB; ++r) {
                float4 xv = ((const float4*)xs[r])[k4];   // LDS broadcast
                acc[r] = fmaf(xv.x, w0, fmaf(xv.y, w1, fmaf(xv.z, w2,
                         fmaf(xv.w, w3, acc[r]))));
            }
        }
        // h2 stores first (overlap with reduce latency)
#pragma unroll
        for (int r = 0; r < RPB; ++r)
            h2[(size_t)(i0 + r) * FDIM + t] = acc[r];
        // layer-2 scores: head = wv; features of head wv live exactly in wave wv
        const float as2v = as2[t], ad2v = ad2[t];
#pragma unroll
        for (int r = 0; r < RPB; ++r) {
            float s = wsum(acc[r] * as2v);
            float d = wsum(acc[r] * ad2v);
            if (lane == 0) {
                es2[(i0 + r) * HEADS + wv] = s;
                ed2[(i0 + r) * HEADS + wv] = d;
            }
        }
    }
}

// K2: layer-2 aggregate + bias + relu + fc, output nodes only.
__global__ void k_agg2fc(const float* __restrict__ h, const float* __restrict__ es,
                         const float* __restrict__ ed, const int* __restrict__ cnt,
                         const int* __restrict__ idx, const float* __restrict__ bias,
                         const float* __restrict__ fw, const float* __restrict__ fb,
                         float* __restrict__ out) {
    __shared__ int   s_idx[MAXNBR];
    __shared__ float s_e[MAXNBR * HEADS];
    __shared__ float s_ed[HEADS];
    __shared__ float s_red[8];
    int q = blockIdx.x;
    int i = MPTS + q;
    int t = threadIdx.x;
    int c = cnt[i];
    if (t < c) s_idx[t] = idx[i * MAXNBR + t];
    if (t < HEADS) s_ed[t] = ed[i * HEADS + t];
    __syncthreads();
    if (t < c * HEADS) {
        int jl = t >> 2, hh = t & 3;
        float e = s_ed[hh] + es[s_idx[jl] * HEADS + hh];
        e = (e >= 0.f) ? e : NSLOPE * e;
        s_e[jl * HEADS + hh] = e;
    }
    __syncthreads();
    int hh = t >> 6;
    float m = -1e30f;
    for (int jl = 0; jl < c; ++jl) m = fmaxf(m, s_e[jl * HEADS + hh]);
    float ssum = 0.f, acc = 0.f;
    for (int jl = 0; jl < c; ++jl) {
        float p = __expf(s_e[jl * HEADS + hh] - m);
        ssum += p;
        acc = fmaf(p, h[s_idx[jl] * FDIM + t], acc);
    }
    float v = fmaxf(acc / ssum + bias[t], 0.f);
    float p0 = v * fw[t * OUTC + 0];
    float p1 = v * fw[t * OUTC + 1];
    for (int off = 32; off; off >>= 1) {
        p0 += __shfl_down(p0, off, 64);
        p1 += __shfl_down(p1, off, 64);
    }
    if ((t & 63) == 0) {
        s_red[(t >> 6) * 2 + 0] = p0;
        s_red[(t >> 6) * 2 + 1] = p1;
    }
    __syncthreads();
    if (t == 0) {
        out[q * OUTC + 0] = s_red[0] + s_red[2] + s_red[4] + s_red[6] + fb[0];
        out[q * OUTC + 1] = s_red[1] + s_red[3] + s_red[5] + s_red[7] + fb[1];
    }
}

extern "C" void kernel_launch(void* const* d_in, const int* in_sizes, int n_in,
                              void* d_out, int out_size, void* d_ws, size_t ws_size,
                              hipStream_t stream) {
    const float* pos   = (const float*)d_in[0];
    const float* pnm   = (const float*)d_in[1];
    const float* W1    = (const float*)d_in[2];
    const float* asrc1 = (const float*)d_in[3];
    const float* adst1 = (const float*)d_in[4];
    const float* b1    = (const float*)d_in[5];
    const float* W2    = (const float*)d_in[6];
    const float* asrc2 = (const float*)d_in[7];
    const float* adst2 = (const float*)d_in[8];
    const float* b2    = (const float*)d_in[9];
    const float* fcw   = (const float*)d_in[10];
    const float* fcb   = (const float*)d_in[11];
    float* out = (float*)d_out;

    float* w    = (float*)d_ws;
    float* es2  = w + OFF_ES2;
    float* ed2  = w + OFF_ED2;
    float* h2   = w + OFF_H2;
    int* nbr_cnt = (int*)((char*)d_ws + (size_t)4 * OFF_END);
    int* nbr_idx = nbr_cnt + KNODES;

    // K1: nbr + layer-1 (rank-3 collapse) + gemm2 + scores2
    k_l1<<<KNODES / RPB, 256, 0, stream>>>(pos, pnm, W1, asrc1, adst1, b1,
                                           W2, asrc2, adst2, h2, es2, ed2,
                                           nbr_cnt, nbr_idx);
    // K2: layer-2 aggregate + fc
    k_agg2fc<<<MPTS, FDIM, 0, stream>>>(h2, es2, ed2, nbr_cnt, nbr_idx, b2,
                                        fcw, fcb, out);
}

// Round 8
// 138.792 us; speedup vs baseline: 1.1645x; 1.1645x over previous
//
#include <hip/hip_runtime.h>

// Problem constants
#define NPTS   3000
#define MPTS   3000
#define KNODES 6000
#define HEADS  4
#define FDIM   256      // HEADS*HID
#define OUTC   2
#define R2     0.0025f
#define NSLOPE 0.2f
#define MAXNBR 64
#define RPB    8        // rows per block (K1,K2) -> 750 blocks

// ---------------- workspace layout (floats) ----------------
#define OFF_ES2  0
#define OFF_ED2  24000
#define OFF_X    48000        // 6000*256
#define OFF_H2   1584000      // 6000*256
#define OFF_END  3120000      // floats; int region starts at byte 4*OFF_END

// full-wave sum: butterfly xor-reduce, all 64 lanes end with the total
__device__ __forceinline__ float wsum(float v) {
#pragma unroll
    for (int off = 32; off; off >>= 1) v += __shfl_xor(v, off, 64);
    return v;
}

// K1: radius scan + FULLY-collapsed layer-1.
// h1 = pts@W1 is rank-3 => x[i,t] = ReLU(q_{i,h(t)} . W1[:,t] + b1[t]),
// q_{i,h} = sum_j alpha^h_ij p_j (3-vector). Scores: e = v_h.p_i + u_h.p_j,
// u_h = W1^T a_src|h, v_h = W1^T a_dst|h (computed once per block).
__global__ __launch_bounds__(256) void k_nbrx(
        const float* __restrict__ pos, const float* __restrict__ pnm,
        const float* __restrict__ W1, const float* __restrict__ as1,
        const float* __restrict__ ad1, const float* __restrict__ b1,
        float* __restrict__ x, int* __restrict__ cnt, int* __restrict__ idx) {
    __shared__ int   s_cnt[RPB];
    __shared__ int   s_idx[RPB][MAXNBR];
    __shared__ float s_u[HEADS][3], s_v[HEADS][3];
    __shared__ float s_q[RPB][HEADS][3];
    const int t = threadIdx.x;
    const int i0 = blockIdx.x * RPB;
    if (t < RPB) s_cnt[t] = 0;

    // u,v per head (wave wv == head wv; xor-reduce leaves sum in all lanes)
    const float w1a = W1[t], w1b = W1[FDIM + t], w1c = W1[2 * FDIM + t];
    {
        const float asv = as1[t], adv = ad1[t];
        float u0 = wsum(w1a * asv), u1 = wsum(w1b * asv), u2 = wsum(w1c * asv);
        float v0 = wsum(w1a * adv), v1 = wsum(w1b * adv), v2 = wsum(w1c * adv);
        if ((t & 63) == 0) {
            int h = t >> 6;
            s_u[h][0] = u0; s_u[h][1] = u1; s_u[h][2] = u2;
            s_v[h][0] = v0; s_v[h][1] = v1; s_v[h][2] = v2;
        }
    }
    __syncthreads();

    // ---- Phase A: neighbor scan (exact fp32 ops -> bit-identical mask) ----
    // 3000 % RPB == 0 -> a block's rows never straddle pos/pnm
    const float* base = (i0 < NPTS) ? pos : pnm;
    const int ib = (i0 < NPTS) ? i0 : i0 - NPTS;
    float xi[RPB], yi[RPB], zi[RPB], si[RPB];
#pragma unroll
    for (int r = 0; r < RPB; ++r) {
        float px = base[ib + r], py = base[NPTS + ib + r], pz = base[2 * NPTS + ib + r];
        xi[r] = px; yi[r] = py; zi[r] = pz;
        si[r] = __fadd_rn(__fadd_rn(__fmul_rn(px, px), __fmul_rn(py, py)),
                          __fmul_rn(pz, pz));
    }
    for (int j = t; j < KNODES; j += 256) {
        float xj, yj, zj;
        if (j < NPTS) { xj = pos[j]; yj = pos[NPTS + j]; zj = pos[2 * NPTS + j]; }
        else { int q = j - NPTS; xj = pnm[q]; yj = pnm[MPTS + q]; zj = pnm[2 * MPTS + q]; }
        float sj = __fadd_rn(__fadd_rn(__fmul_rn(xj, xj), __fmul_rn(yj, yj)),
                             __fmul_rn(zj, zj));
#pragma unroll
        for (int r = 0; r < RPB; ++r) {
            float dot = __fadd_rn(__fadd_rn(__fmul_rn(xi[r], xj), __fmul_rn(yi[r], yj)),
                                  __fmul_rn(zi[r], zj));
            float d2 = __fsub_rn(__fadd_rn(si[r], sj), __fmul_rn(2.0f, dot));
            if (d2 < R2) {
                int p = atomicAdd(&s_cnt[r], 1);
                if (p < MAXNBR) s_idx[r][p] = j;
            }
        }
    }
    __syncthreads();
    if (t < RPB) cnt[i0 + t] = min(s_cnt[t], MAXNBR);
#pragma unroll
    for (int r = 0; r < RPB; ++r) {
        int c = min(s_cnt[r], MAXNBR);
        if (t < c) idx[(i0 + r) * MAXNBR + t] = s_idx[r][t];
    }

    // ---- Phase B: per-(row,head) softmax -> weighted 3-vector q ----
    // pair = t & 31 (8 rows x 4 heads); threads 32.. duplicate harmlessly.
    {
        const int pr = (t & 31) >> 2, h = t & 3;
        const int c = min(s_cnt[pr], MAXNBR);
        const float u0 = s_u[h][0], u1 = s_u[h][1], u2 = s_u[h][2];
        const float dsum = fmaf(xi[pr], s_v[h][0],
                           fmaf(yi[pr], s_v[h][1], zi[pr] * s_v[h][2]));
        float m = -1e30f;
        for (int jl = 0; jl < c; ++jl) {
            int j = s_idx[pr][jl];
            float xj, yj, zj;
            if (j < NPTS) { xj = pos[j]; yj = pos[NPTS + j]; zj = pos[2 * NPTS + j]; }
            else { int q = j - NPTS; xj = pnm[q]; yj = pnm[MPTS + q]; zj = pnm[2 * MPTS + q]; }
            float e = dsum + fmaf(xj, u0, fmaf(yj, u1, zj * u2));
            e = (e >= 0.f) ? e : NSLOPE * e;
            m = fmaxf(m, e);
        }
        float S = 0.f, q0 = 0.f, q1 = 0.f, q2 = 0.f;
        for (int jl = 0; jl < c; ++jl) {
            int j = s_idx[pr][jl];
            float xj, yj, zj;
            if (j < NPTS) { xj = pos[j]; yj = pos[NPTS + j]; zj = pos[2 * NPTS + j]; }
            else { int q = j - NPTS; xj = pnm[q]; yj = pnm[MPTS + q]; zj = pnm[2 * MPTS + q]; }
            float e = dsum + fmaf(xj, u0, fmaf(yj, u1, zj * u2));
            e = (e >= 0.f) ? e : NSLOPE * e;      // identical sequence as pass 1
            float a = __expf(e - m);
            S += a;
            q0 = fmaf(a, xj, q0); q1 = fmaf(a, yj, q1); q2 = fmaf(a, zj, q2);
        }
        if (t < 32) {
            float inv = 1.f / S;
            s_q[pr][h][0] = q0 * inv;
            s_q[pr][h][1] = q1 * inv;
            s_q[pr][h][2] = q2 * inv;
        }
    }
    __syncthreads();

    // ---- Phase C: x[i,t] = ReLU(q . W1[:,t] + b1[t]) ----
    {
        const float b1v = b1[t];
        const int h = t >> 6;
#pragma unroll
        for (int r = 0; r < RPB; ++r) {
            float q0 = s_q[r][h][0], q1 = s_q[r][h][1], q2 = s_q[r][h][2];
            float v = fmaf(q0, w1a, fmaf(q1, w1b, q2 * w1c)) + b1v;
            x[(size_t)(i0 + r) * FDIM + t] = fmaxf(v, 0.f);
        }
    }
}

// K2: h2 = x @ W2 + layer-2 scores. Col-per-thread (col = t): W2 read once
// per block (coalesced dword, 750*256KB = 192 MB L2); x rows via
// wave-uniform base -> s_load (scalar pipe, no VALU/LDS cost). head = wave.
__global__ __launch_bounds__(256) void k_gemm2(
        const float* __restrict__ x, const float* __restrict__ W2,
        const float* __restrict__ as2, const float* __restrict__ ad2,
        float* __restrict__ h2, float* __restrict__ es2, float* __restrict__ ed2) {
    const int t = threadIdx.x;
    const int i0 = __builtin_amdgcn_readfirstlane(blockIdx.x * RPB);
    float acc[RPB];
#pragma unroll
    for (int r = 0; r < RPB; ++r) acc[r] = 0.f;
#pragma unroll 2
    for (int k4 = 0; k4 < FDIM / 4; ++k4) {
        float w0 = W2[(4 * k4 + 0) * FDIM + t];
        float w1 = W2[(4 * k4 + 1) * FDIM + t];
        float w2 = W2[(4 * k4 + 2) * FDIM + t];
        float w3 = W2[(4 * k4 + 3) * FDIM + t];
#pragma unroll
        for (int r = 0; r < RPB; ++r) {
            float4 xv = *(const float4*)(x + (size_t)(i0 + r) * FDIM + 4 * k4);
            acc[r] = fmaf(xv.x, w0, fmaf(xv.y, w1, fmaf(xv.z, w2,
                     fmaf(xv.w, w3, acc[r]))));
        }
    }
#pragma unroll
    for (int r = 0; r < RPB; ++r)
        h2[(size_t)(i0 + r) * FDIM + t] = acc[r];
    const float as2v = as2[t], ad2v = ad2[t];
    const int wv = t >> 6, lane = t & 63;
#pragma unroll
    for (int r = 0; r < RPB; ++r) {
        float s = wsum(acc[r] * as2v);
        float d = wsum(acc[r] * ad2v);
        if (lane == 0) {
            es2[(i0 + r) * HEADS + wv] = s;
            ed2[(i0 + r) * HEADS + wv] = d;
        }
    }
}

// K3: layer-2 aggregate + bias + relu + fc, output nodes only.
__global__ void k_agg2fc(const float* __restrict__ h, const float* __restrict__ es,
                         const float* __restrict__ ed, const int* __restrict__ cnt,
                         const int* __restrict__ idx, const float* __restrict__ bias,
                         const float* __restrict__ fw, const float* __restrict__ fb,
                         float* __restrict__ out) {
    __shared__ int   s_idx[MAXNBR];
    __shared__ float s_e[MAXNBR * HEADS];
    __shared__ float s_ed[HEADS];
    __shared__ float s_red[8];
    int q = blockIdx.x;
    int i = MPTS + q;
    int t = threadIdx.x;
    int c = cnt[i];
    if (t < c) s_idx[t] = idx[i * MAXNBR + t];
    if (t < HEADS) s_ed[t] = ed[i * HEADS + t];
    __syncthreads();
    if (t < c * HEADS) {
        int jl = t >> 2, hh = t & 3;
        float e = s_ed[hh] + es[s_idx[jl] * HEADS + hh];
        e = (e >= 0.f) ? e : NSLOPE * e;
        s_e[jl * HEADS + hh] = e;
    }
    __syncthreads();
    int hh = t >> 6;
    float m = -1e30f;
    for (int jl = 0; jl < c; ++jl) m = fmaxf(m, s_e[jl * HEADS + hh]);
    float ssum = 0.f, acc = 0.f;
    for (int jl = 0; jl < c; ++jl) {
        float p = __expf(s_e[jl * HEADS + hh] - m);
        ssum += p;
        acc = fmaf(p, h[s_idx[jl] * FDIM + t], acc);
    }
    float v = fmaxf(acc / ssum + bias[t], 0.f);
    float p0 = v * fw[t * OUTC + 0];
    float p1 = v * fw[t * OUTC + 1];
    for (int off = 32; off; off >>= 1) {
        p0 += __shfl_down(p0, off, 64);
        p1 += __shfl_down(p1, off, 64);
    }
    if ((t & 63) == 0) {
        s_red[(t >> 6) * 2 + 0] = p0;
        s_red[(t >> 6) * 2 + 1] = p1;
    }
    __syncthreads();
    if (t == 0) {
        out[q * OUTC + 0] = s_red[0] + s_red[2] + s_red[4] + s_red[6] + fb[0];
        out[q * OUTC + 1] = s_red[1] + s_red[3] + s_red[5] + s_red[7] + fb[1];
    }
}

extern "C" void kernel_launch(void* const* d_in, const int* in_sizes, int n_in,
                              void* d_out, int out_size, void* d_ws, size_t ws_size,
                              hipStream_t stream) {
    const float* pos   = (const float*)d_in[0];
    const float* pnm   = (const float*)d_in[1];
    const float* W1    = (const float*)d_in[2];
    const float* asrc1 = (const float*)d_in[3];
    const float* adst1 = (const float*)d_in[4];
    const float* b1    = (const float*)d_in[5];
    const float* W2    = (const float*)d_in[6];
    const float* asrc2 = (const float*)d_in[7];
    const float* adst2 = (const float*)d_in[8];
    const float* b2    = (const float*)d_in[9];
    const float* fcw   = (const float*)d_in[10];
    const float* fcb   = (const float*)d_in[11];
    float* out = (float*)d_out;

    float* w    = (float*)d_ws;
    float* es2  = w + OFF_ES2;
    float* ed2  = w + OFF_ED2;
    float* x    = w + OFF_X;
    float* h2   = w + OFF_H2;
    int* nbr_cnt = (int*)((char*)d_ws + (size_t)4 * OFF_END);
    int* nbr_idx = nbr_cnt + KNODES;

    // K1: nbr scan + fully-collapsed layer-1 -> x
    k_nbrx<<<KNODES / RPB, 256, 0, stream>>>(pos, pnm, W1, asrc1, adst1, b1,
                                             x, nbr_cnt, nbr_idx);
    // K2: h2 = x@W2 + layer-2 scores
    k_gemm2<<<KNODES / RPB, 256, 0, stream>>>(x, W2, asrc2, adst2, h2, es2, ed2);
    // K3: layer-2 aggregate + fc
    k_agg2fc<<<MPTS, FDIM, 0, stream>>>(h2, es2, ed2, nbr_cnt, nbr_idx, b2,
                                        fcw, fcb, out);
}

// Round 9
// 128.903 us; speedup vs baseline: 1.2538x; 1.0767x over previous
//
#include <hip/hip_runtime.h>

// Problem constants
#define NPTS   3000
#define MPTS   3000
#define KNODES 6000
#define HEADS  4
#define FDIM   256      // HEADS*HID
#define OUTC   2
#define R2     0.0025f
#define NSLOPE 0.2f
#define MAXNBR 64
#define RPB    8        // rows per K1 block -> 750 blocks (~3/CU)

// ---------------- workspace layout (floats) ----------------
#define OFF_ES2  0
#define OFF_ED2  24000
#define OFF_H2   48000        // 6000*256
#define OFF_END  1584000      // floats; int region starts at byte 4*OFF_END

// full-wave sum: butterfly xor-reduce, all 64 lanes end with the total
__device__ __forceinline__ float wsum(float v) {
#pragma unroll
    for (int off = 32; off; off >>= 1) v += __shfl_xor(v, off, 64);
    return v;
}

// K1: one kernel, block-local through h2 (x never touches HBM):
//  A) radius scan (exact fp32 gram-trick ops -> bit-identical mask);
//     neighbor coords cached in LDS at hit time (no scattered reloads)
//  B) fully-collapsed layer-1: 32 (row,head) pairs in parallel ->
//     q_{i,h} = sum_j alpha_ij p_j (3-vector), from LDS coords only
//  C) x[i,t] = ReLU(q.W1[:,t]+b1[t]) -> LDS; gemm2 col-per-thread
//     (W2 read once per block, coalesced) + layer-2 scores (head=wave)
__global__ __launch_bounds__(256) void k_main(
        const float* __restrict__ pos, const float* __restrict__ pnm,
        const float* __restrict__ W1, const float* __restrict__ as1,
        const float* __restrict__ ad1, const float* __restrict__ b1,
        const float* __restrict__ W2, const float* __restrict__ as2,
        const float* __restrict__ ad2,
        float* __restrict__ h2, float* __restrict__ es2, float* __restrict__ ed2,
        int* __restrict__ cnt, int* __restrict__ idx) {
    __shared__ int   s_cnt[RPB];
    __shared__ int   s_idx[RPB][MAXNBR];
    __shared__ float s_nx[RPB][MAXNBR], s_ny[RPB][MAXNBR], s_nz[RPB][MAXNBR];
    __shared__ float s_u[HEADS][3], s_v[HEADS][3];
    __shared__ float s_q[RPB][HEADS][3];
    __shared__ __align__(16) float xs[RPB][FDIM];
    const int t = threadIdx.x;
    const int i0 = blockIdx.x * RPB;
    if (t < RPB) s_cnt[t] = 0;

    // u,v per head (wave == head; xor-reduce leaves sum in all lanes)
    const float w1a = W1[t], w1b = W1[FDIM + t], w1c = W1[2 * FDIM + t];
    {
        const float asv = as1[t], adv = ad1[t];
        float u0 = wsum(w1a * asv), u1 = wsum(w1b * asv), u2 = wsum(w1c * asv);
        float v0 = wsum(w1a * adv), v1 = wsum(w1b * adv), v2 = wsum(w1c * adv);
        if ((t & 63) == 0) {
            int h = t >> 6;
            s_u[h][0] = u0; s_u[h][1] = u1; s_u[h][2] = u2;
            s_v[h][0] = v0; s_v[h][1] = v1; s_v[h][2] = v2;
        }
    }
    __syncthreads();

    // ---- Phase A: neighbor scan (exact fp32 ops -> bit-identical mask) ----
    // 3000 % RPB == 0 -> a block's rows never straddle pos/pnm
    const float* base = (i0 < NPTS) ? pos : pnm;
    const int ib = (i0 < NPTS) ? i0 : i0 - NPTS;
    float xi[RPB], yi[RPB], zi[RPB], si[RPB];
#pragma unroll
    for (int r = 0; r < RPB; ++r) {
        float px = base[ib + r], py = base[NPTS + ib + r], pz = base[2 * NPTS + ib + r];
        xi[r] = px; yi[r] = py; zi[r] = pz;
        si[r] = __fadd_rn(__fadd_rn(__fmul_rn(px, px), __fmul_rn(py, py)),
                          __fmul_rn(pz, pz));
    }
    for (int j = t; j < KNODES; j += 256) {
        float xj, yj, zj;
        if (j < NPTS) { xj = pos[j]; yj = pos[NPTS + j]; zj = pos[2 * NPTS + j]; }
        else { int q = j - NPTS; xj = pnm[q]; yj = pnm[MPTS + q]; zj = pnm[2 * MPTS + q]; }
        float sj = __fadd_rn(__fadd_rn(__fmul_rn(xj, xj), __fmul_rn(yj, yj)),
                             __fmul_rn(zj, zj));
#pragma unroll
        for (int r = 0; r < RPB; ++r) {
            float dot = __fadd_rn(__fadd_rn(__fmul_rn(xi[r], xj), __fmul_rn(yi[r], yj)),
                                  __fmul_rn(zi[r], zj));
            float d2 = __fsub_rn(__fadd_rn(si[r], sj), __fmul_rn(2.0f, dot));
            if (d2 < R2) {
                int p = atomicAdd(&s_cnt[r], 1);
                if (p < MAXNBR) {
                    s_idx[r][p] = j;
                    s_nx[r][p] = xj; s_ny[r][p] = yj; s_nz[r][p] = zj;
                }
            }
        }
    }
    __syncthreads();
    if (t < RPB) cnt[i0 + t] = min(s_cnt[t], MAXNBR);
#pragma unroll
    for (int r = 0; r < RPB; ++r) {
        int c = min(s_cnt[r], MAXNBR);
        if (t < c) idx[(i0 + r) * MAXNBR + t] = s_idx[r][t];
    }

    // ---- Phase B: per-(row,head) softmax -> weighted 3-vector q ----
    // 32 pairs (8 rows x 4 heads) run in parallel on threads 0..31;
    // threads 32+ duplicate harmlessly (writes gated to t<32). LDS-only reads.
    {
        const int pr = (t & 31) >> 2, h = t & 3;
        const int c = min(s_cnt[pr], MAXNBR);
        const float u0 = s_u[h][0], u1 = s_u[h][1], u2 = s_u[h][2];
        const float dsum = fmaf(xi[pr], s_v[h][0],
                           fmaf(yi[pr], s_v[h][1], zi[pr] * s_v[h][2]));
        float m = -1e30f;
        for (int jl = 0; jl < c; ++jl) {
            float e = dsum + fmaf(s_nx[pr][jl], u0,
                             fmaf(s_ny[pr][jl], u1, s_nz[pr][jl] * u2));
            e = (e >= 0.f) ? e : NSLOPE * e;
            m = fmaxf(m, e);
        }
        float S = 0.f, q0 = 0.f, q1 = 0.f, q2 = 0.f;
        for (int jl = 0; jl < c; ++jl) {
            float xj = s_nx[pr][jl], yj = s_ny[pr][jl], zj = s_nz[pr][jl];
            float e = dsum + fmaf(xj, u0, fmaf(yj, u1, zj * u2));
            e = (e >= 0.f) ? e : NSLOPE * e;      // identical sequence as pass 1
            float a = __expf(e - m);
            S += a;
            q0 = fmaf(a, xj, q0); q1 = fmaf(a, yj, q1); q2 = fmaf(a, zj, q2);
        }
        if (t < 32) {
            float inv = 1.f / S;
            s_q[pr][h][0] = q0 * inv;
            s_q[pr][h][1] = q1 * inv;
            s_q[pr][h][2] = q2 * inv;
        }
    }
    __syncthreads();

    // ---- Phase C: x -> LDS, then gemm2 + layer-2 scores ----
    {
        const float b1v = b1[t];
        const int h = t >> 6;
#pragma unroll
        for (int r = 0; r < RPB; ++r) {
            float q0 = s_q[r][h][0], q1 = s_q[r][h][1], q2 = s_q[r][h][2];
            float v = fmaf(q0, w1a, fmaf(q1, w1b, q2 * w1c)) + b1v;
            xs[r][t] = fmaxf(v, 0.f);
        }
    }
    __syncthreads();
    {
        float acc[RPB];
#pragma unroll
        for (int r = 0; r < RPB; ++r) acc[r] = 0.f;
#pragma unroll 2
        for (int k4 = 0; k4 < FDIM / 4; ++k4) {
            float w0 = W2[(4 * k4 + 0) * FDIM + t];   // coalesced, once/block
            float w1 = W2[(4 * k4 + 1) * FDIM + t];
            float w2 = W2[(4 * k4 + 2) * FDIM + t];
            float w3 = W2[(4 * k4 + 3) * FDIM + t];
#pragma unroll
            for (int r = 0; r < RPB; ++r) {
                float4 xv = ((const float4*)xs[r])[k4];   // LDS broadcast
                acc[r] = fmaf(xv.x, w0, fmaf(xv.y, w1, fmaf(xv.z, w2,
                         fmaf(xv.w, w3, acc[r]))));
            }
        }
#pragma unroll
        for (int r = 0; r < RPB; ++r)
            h2[(size_t)(i0 + r) * FDIM + t] = acc[r];
        const float as2v = as2[t], ad2v = ad2[t];
        const int wv = t >> 6, lane = t & 63;
#pragma unroll
        for (int r = 0; r < RPB; ++r) {
            float s = wsum(acc[r] * as2v);
            float d = wsum(acc[r] * ad2v);
            if (lane == 0) {
                es2[(i0 + r) * HEADS + wv] = s;
                ed2[(i0 + r) * HEADS + wv] = d;
            }
        }
    }
}

// K2: layer-2 aggregate + bias + relu + fc, output nodes only.
__global__ void k_agg2fc(const float* __restrict__ h, const float* __restrict__ es,
                         const float* __restrict__ ed, const int* __restrict__ cnt,
                         const int* __restrict__ idx, const float* __restrict__ bias,
                         const float* __restrict__ fw, const float* __restrict__ fb,
                         float* __restrict__ out) {
    __shared__ int   s_idx[MAXNBR];
    __shared__ float s_e[MAXNBR * HEADS];
    __shared__ float s_ed[HEADS];
    __shared__ float s_red[8];
    int q = blockIdx.x;
    int i = MPTS + q;
    int t = threadIdx.x;
    int c = cnt[i];
    if (t < c) s_idx[t] = idx[i * MAXNBR + t];
    if (t < HEADS) s_ed[t] = ed[i * HEADS + t];
    __syncthreads();
    if (t < c * HEADS) {
        int jl = t >> 2, hh = t & 3;
        float e = s_ed[hh] + es[s_idx[jl] * HEADS + hh];
        e = (e >= 0.f) ? e : NSLOPE * e;
        s_e[jl * HEADS + hh] = e;
    }
    __syncthreads();
    int hh = t >> 6;
    float m = -1e30f;
    for (int jl = 0; jl < c; ++jl) m = fmaxf(m, s_e[jl * HEADS + hh]);
    float ssum = 0.f, acc = 0.f;
    for (int jl = 0; jl < c; ++jl) {
        float p = __expf(s_e[jl * HEADS + hh] - m);
        ssum += p;
        acc = fmaf(p, h[s_idx[jl] * FDIM + t], acc);
    }
    float v = fmaxf(acc / ssum + bias[t], 0.f);
    float p0 = v * fw[t * OUTC + 0];
    float p1 = v * fw[t * OUTC + 1];
    for (int off = 32; off; off >>= 1) {
        p0 += __shfl_down(p0, off, 64);
        p1 += __shfl_down(p1, off, 64);
    }
    if ((t & 63) == 0) {
        s_red[(t >> 6) * 2 + 0] = p0;
        s_red[(t >> 6) * 2 + 1] = p1;
    }
    __syncthreads();
    if (t == 0) {
        out[q * OUTC + 0] = s_red[0] + s_red[2] + s_red[4] + s_red[6] + fb[0];
        out[q * OUTC + 1] = s_red[1] + s_red[3] + s_red[5] + s_red[7] + fb[1];
    }
}

extern "C" void kernel_launch(void* const* d_in, const int* in_sizes, int n_in,
                              void* d_out, int out_size, void* d_ws, size_t ws_size,
                              hipStream_t stream) {
    const float* pos   = (const float*)d_in[0];
    const float* pnm   = (const float*)d_in[1];
    const float* W1    = (const float*)d_in[2];
    const float* asrc1 = (const float*)d_in[3];
    const float* adst1 = (const float*)d_in[4];
    const float* b1    = (const float*)d_in[5];
    const float* W2    = (const float*)d_in[6];
    const float* asrc2 = (const float*)d_in[7];
    const float* adst2 = (const float*)d_in[8];
    const float* b2    = (const float*)d_in[9];
    const float* fcw   = (const float*)d_in[10];
    const float* fcb   = (const float*)d_in[11];
    float* out = (float*)d_out;

    float* w    = (float*)d_ws;
    float* es2  = w + OFF_ES2;
    float* ed2  = w + OFF_ED2;
    float* h2   = w + OFF_H2;
    int* nbr_cnt = (int*)((char*)d_ws + (size_t)4 * OFF_END);
    int* nbr_idx = nbr_cnt + KNODES;

    // K1: scan + collapsed layer-1 + gemm2 + scores2 (x stays in LDS)
    k_main<<<KNODES / RPB, 256, 0, stream>>>(pos, pnm, W1, asrc1, adst1, b1,
                                             W2, asrc2, adst2, h2, es2, ed2,
                                             nbr_cnt, nbr_idx);
    // K2: layer-2 aggregate + fc
    k_agg2fc<<<MPTS, FDIM, 0, stream>>>(h2, es2, ed2, nbr_cnt, nbr_idx, b2,
                                        fcw, fcb, out);
}